// Round 9
// baseline (201041.150 us; speedup 1.0000x reference)
//
#include <hip/hip_runtime.h>

#define HID 512
#define NB  64
#define NT  1024
#define THX 0.1f
#define THH 0.05f

// ---- prep: pack W_ih_l0 [1536][6] f32 -> [6][512]{r,z,n} float3 ----
__global__ void pack_ih0(const float* __restrict__ src, float* __restrict__ dst) {
    int idx = blockIdx.x * blockDim.x + threadIdx.x;
    if (idx < 6 * HID) {
        int f = idx / HID, j = idx % HID;
        dst[f * 1536 + j * 3 + 0] = src[(0 * HID + j) * 6 + f];
        dst[f * 1536 + j * 3 + 1] = src[(1 * HID + j) * 6 + f];
        dst[f * 1536 + j * 3 + 2] = src[(2 * HID + j) * 6 + f];
    }
}

// ---- prep: pack a [1536][512] f32 matrix -> [512(k)][512(j)]{r,z,n} float3 ----
__global__ void pack_h3(const float* __restrict__ src, float* __restrict__ dst) {
    int idx = blockIdx.x * blockDim.x + threadIdx.x;
    if (idx < HID * HID) {
        int k = idx / HID, j = idx % HID;
        dst[k * 1536 + j * 3 + 0] = src[(0 * HID + j) * HID + k];
        dst[k * 1536 + j * 3 + 1] = src[(1 * HID + j) * HID + k];
        dst[k * 1536 + j * 3 + 2] = src[(2 * HID + j) * HID + k];
    }
}

// ---- init: zero list counts + quad-barrier counters (every launch) ----
__global__ void init_ws(int* __restrict__ cnts, int* __restrict__ bars) {
    int i = blockIdx.x * blockDim.x + threadIdx.x;
    if (i < 3 * 2 * NB * 2) cnts[i] = 0;
    if (i < NB) bars[i] = 0;
}

__device__ __forceinline__ int cidx(int kind, int slot, int b, int half) {
    return ((kind * 2 + slot) * NB + b) * 2 + half;
}
__device__ __forceinline__ int lofs(int kind, int slot, int b, int half) {
    return (((kind * 2 + slot) * NB + b) * 2 + half) * 256;   // uint2 units
}

// ---- main kernel: 256 WGs = 64 batches x {L0,L1} x {j-half lo,hi} ----
// 1024 threads/WG: unit u = tid>>2 (256 units/WG), role = tid&3:
//   role0 -> ar, role1 -> az, role2 -> an (ih lists) / anh (hh lists), role3 idle.
// Per-gate accumulation order identical to rounds 3-8 (no reassociation).
// Quad sync: per-batch monotone atomic counter, 1 barrier/iteration.
__global__ __launch_bounds__(1024)
void dgru_split(const float* __restrict__ x,
                const float* __restrict__ wih0p,   // [6][512] float3
                const float* __restrict__ whh0p,   // [512][512] float3
                const float* __restrict__ wih1p,
                const float* __restrict__ whh1p,
                const float* __restrict__ bih0, const float* __restrict__ bhh0,
                const float* __restrict__ bih1, const float* __restrict__ bhh1,
                const float* __restrict__ wfc,
                uint2* __restrict__ lists, int* __restrict__ cnts,
                int* __restrict__ bars, float* __restrict__ ws_fc) {
    __shared__ float s_x[2 * NT];                  // 8 KB (L0 only)
    __shared__ float s_dx0[8];
    __shared__ float s_xp0[8];
    __shared__ uint2 s_l1[HID + 8];
    __shared__ uint2 s_l2[HID + 8];
    __shared__ int   s_c1[16], s_c2[16];
    __shared__ float s_fcp[16][2];

    const int wgid  = blockIdx.x;
    const int bq    = wgid >> 2;
    const int layer = (wgid >> 1) & 1;
    const int half  = wgid & 1;
    const int tid   = threadIdx.x;
    const int lane  = tid & 63;
    const int wave  = tid >> 6;
    const int u     = tid >> 2;
    const int role  = tid & 3;
    const int uu    = half * 256 + u;

    const float* bih = layer ? bih1 : bih0;
    const float* bhh = layer ? bhh1 : bhh0;

    // carries: accP = {ar | az | an} by role; accS = anh on role2
    float accP = 0.f, accS = 0.f;
    if (role == 0)      accP = bih[uu]         + bhh[uu];
    else if (role == 1) accP = bih[HID + uu]   + bhh[HID + uu];
    else if (role == 2) { accP = bih[2*HID + uu]; accS = bhh[2*HID + uu]; }

    float h = 0.f, hp = 0.f, xp1 = 0.f;
    float wfc0 = 0.f, wfc1 = 0.f;
    if (layer == 1) { wfc0 = wfc[uu]; wfc1 = wfc[HID + uu]; }

    if (layer == 0)
        for (int i = tid; i < 2 * NT; i += 1024) s_x[i] = x[bq * 2 * NT + i];
    if (tid < 8) { s_xp0[tid] = 0.f; s_dx0[tid] = 0.f; }
    __syncthreads();

    for (int t = 0; t <= NT; ++t) {
        const int rs = t & 1, ps = (t + 1) & 1;
        if (layer == 0) {
            if (t < NT) {
                // ---- stage merged listA(rs): lo sublist then hi (k ascending) ----
                int cLo = cnts[cidx(0, rs, bq, 0)];
                int cHi = cnts[cidx(0, rs, bq, 1)];
                int ntot = cLo + cHi, n1 = (ntot + 7) & ~7;
                const uint2* gLo = lists + lofs(0, rs, bq, 0);
                const uint2* gHi = lists + lofs(0, rs, bq, 1);
                if (tid < cLo)       s_l1[tid] = gLo[tid];
                else if (tid < ntot) s_l1[tid] = gHi[tid - cLo];
                else if (tid < n1)   s_l1[tid] = make_uint2(0u, 0u);
                // ---- input features for step t ----
                if (tid < 6) {
                    float iv = s_x[2 * t], qv = s_x[2 * t + 1];
                    float amp = sqrtf(iv * iv + qv * qv);
                    float f;
                    if      (tid == 0) f = iv;
                    else if (tid == 1) f = qv;
                    else if (tid == 2) f = amp;
                    else if (tid == 3) f = amp * amp * amp;
                    else if (tid == 4) f = qv / amp;
                    else               f = iv / amp;
                    float dx = f - s_xp0[tid];
                    if (fabsf(dx) < THX) dx = 0.f; else s_xp0[tid] = f;
                    s_dx0[tid] = dx;
                }
                __syncthreads();
                // ---- dense ih0 (6 features; dv==0 adds exact +0) ----
                #pragma unroll
                for (int f = 0; f < 6; ++f) {
                    float dv = s_dx0[f];
                    float w = wih0p[f * 1536 + uu * 3 + role];   // role3: harmless over-read
                    accP += dv * w;
                }
                // ---- listA MAC over whh0 (hh-type: role2 -> accS) ----
                for (int i = 0; i < n1; ++i) {
                    uint2 e = s_l1[i];
                    float v = __uint_as_float(e.y);
                    float w = whh0p[(int)e.x * 1536 + uu * 3 + role];
                    float tv = v * w;
                    if (role == 2) accS += tv; else accP += tv;
                }
                // ---- gates (role0 meaningful) ----
                const int bl = lane & ~3;
                float ar  = __shfl(accP, bl + 0, 64);
                float az  = __shfl(accP, bl + 1, 64);
                float an  = __shfl(accP, bl + 2, 64);
                float anh = __shfl(accS, bl + 2, 64);
                float r = 1.f / (1.f + expf(-ar));
                float z = 1.f / (1.f + expf(-az));
                float n = tanhf(an + r * anh);
                h = (1.f - z) * n + z * h;
                // ---- deltas + dual compaction (A' = dh0, B' = dx1) ----
                float dA = h - hp;  if (fabsf(dA) < THH) dA = 0.f; else hp = h;
                float dB = h - xp1; if (fabsf(dB) < THX) dB = 0.f; else xp1 = h;
                bool nzA = (role == 0) && (dA != 0.f);
                bool nzB = (role == 0) && (dB != 0.f);
                unsigned long long mA = __ballot(nzA);
                unsigned long long mB = __ballot(nzB);
                if (lane == 0) { s_c1[wave] = __popcll(mA); s_c2[wave] = __popcll(mB); }
                __syncthreads();
                int baseA = 0, baseB = 0, totA = 0, totB = 0;
                #pragma unroll
                for (int w = 0; w < 16; ++w) {
                    int c1 = s_c1[w], c2 = s_c2[w];
                    baseA += (w < wave) ? c1 : 0;  totA += c1;
                    baseB += (w < wave) ? c2 : 0;  totB += c2;
                }
                uint2* outA = lists + lofs(0, ps, bq, half);
                uint2* outB = lists + lofs(1, ps, bq, half);
                unsigned long long below = (1ull << lane) - 1;
                if (nzA) outA[baseA + __popcll(mA & below)] = make_uint2((unsigned)uu, __float_as_uint(dA));
                if (nzB) outB[baseB + __popcll(mB & below)] = make_uint2((unsigned)uu, __float_as_uint(dB));
                if (tid == 0) {
                    cnts[cidx(0, ps, bq, half)] = totA;
                    cnts[cidx(1, ps, bq, half)] = totB;
                }
            }
        } else {
            if (t > 0) {
                // ---- L1 runs step t-1: stage listB(rs) and listC(rs) ----
                int cBlo = cnts[cidx(1, rs, bq, 0)], cBhi = cnts[cidx(1, rs, bq, 1)];
                int cClo = cnts[cidx(2, rs, bq, 0)], cChi = cnts[cidx(2, rs, bq, 1)];
                int ntB = cBlo + cBhi, nB = (ntB + 7) & ~7;
                int ntC = cClo + cChi, nC = (ntC + 7) & ~7;
                const uint2* gBlo = lists + lofs(1, rs, bq, 0);
                const uint2* gBhi = lists + lofs(1, rs, bq, 1);
                const uint2* gClo = lists + lofs(2, rs, bq, 0);
                const uint2* gChi = lists + lofs(2, rs, bq, 1);
                if (tid < cBlo)      s_l1[tid] = gBlo[tid];
                else if (tid < ntB)  s_l1[tid] = gBhi[tid - cBlo];
                else if (tid < nB)   s_l1[tid] = make_uint2(0u, 0u);
                if (tid < cClo)      s_l2[tid] = gClo[tid];
                else if (tid < ntC)  s_l2[tid] = gChi[tid - cClo];
                else if (tid < nC)   s_l2[tid] = make_uint2(0u, 0u);
                __syncthreads();
                // listB over wih1 (ih-type: all roles -> accP)
                for (int i = 0; i < nB; ++i) {
                    uint2 e = s_l1[i];
                    float v = __uint_as_float(e.y);
                    float w = wih1p[(int)e.x * 1536 + uu * 3 + role];
                    accP += v * w;
                }
                // listC over whh1 (hh-type: role2 -> accS)
                for (int i = 0; i < nC; ++i) {
                    uint2 e = s_l2[i];
                    float v = __uint_as_float(e.y);
                    float w = whh1p[(int)e.x * 1536 + uu * 3 + role];
                    float tv = v * w;
                    if (role == 2) accS += tv; else accP += tv;
                }
                const int bl = lane & ~3;
                float ar  = __shfl(accP, bl + 0, 64);
                float az  = __shfl(accP, bl + 1, 64);
                float an  = __shfl(accP, bl + 2, 64);
                float anh = __shfl(accS, bl + 2, 64);
                float r = 1.f / (1.f + expf(-ar));
                float z = 1.f / (1.f + expf(-az));
                float n = tanhf(an + r * anh);
                h = (1.f - z) * n + z * h;
                // FC partials (role0 lanes), tree within wave, serial over waves
                float p0 = (role == 0) ? h * wfc0 : 0.f;
                float p1 = (role == 0) ? h * wfc1 : 0.f;
                p0 += __shfl_down(p0, 4, 64);  p1 += __shfl_down(p1, 4, 64);
                p0 += __shfl_down(p0, 8, 64);  p1 += __shfl_down(p1, 8, 64);
                p0 += __shfl_down(p0, 16, 64); p1 += __shfl_down(p1, 16, 64);
                p0 += __shfl_down(p0, 32, 64); p1 += __shfl_down(p1, 32, 64);
                if (lane == 0) { s_fcp[wave][0] = p0; s_fcp[wave][1] = p1; }
                __syncthreads();
                if (tid == 0) {
                    float q0 = 0.f, q1 = 0.f;
                    #pragma unroll
                    for (int w = 0; w < 16; ++w) { q0 += s_fcp[w][0]; q1 += s_fcp[w][1]; }
                    float2* dst = (float2*)(ws_fc + ((size_t)(bq * NT + (t - 1)) * 2 + half) * 2);
                    *dst = make_float2(q0, q1);
                }
            }
            if (t < NT) {
                // ---- dC publish (dh1 after step t-1) ----
                float dC = h - hp; if (fabsf(dC) < THH) dC = 0.f; else hp = h;
                bool nzC = (role == 0) && (dC != 0.f);
                unsigned long long mC = __ballot(nzC);
                if (lane == 0) s_c1[wave] = __popcll(mC);
                __syncthreads();
                int baseC = 0, totC = 0;
                #pragma unroll
                for (int w = 0; w < 16; ++w) {
                    int c = s_c1[w];
                    baseC += (w < wave) ? c : 0;  totC += c;
                }
                uint2* outC = lists + lofs(2, ps, bq, half);
                if (nzC) outC[baseC + __popcll(mC & ((1ull << lane) - 1))] =
                    make_uint2((unsigned)uu, __float_as_uint(dC));
                if (tid == 0) cnts[cidx(2, ps, bq, half)] = totC;
            }
        }
        // ---- quad barrier (monotone counter, device scope) ----
        if (t < NT) {
            __threadfence();                         // release my stores
            __syncthreads();
            if (tid == 0) {
                __hip_atomic_fetch_add(&bars[bq], 1, __ATOMIC_RELEASE, __HIP_MEMORY_SCOPE_AGENT);
                while (__hip_atomic_load(&bars[bq], __ATOMIC_ACQUIRE, __HIP_MEMORY_SCOPE_AGENT) < 4 * (t + 1))
                    __builtin_amdgcn_s_sleep(2);
            }
            __syncthreads();
            __threadfence();                         // acquire: drop stale cached lines
        }
    }
}

// ---- epilogue: deterministic FC reduction (lo half + hi half + bias) ----
__global__ void fc_reduce(const float* __restrict__ ws_fc,
                          const float* __restrict__ bfc,
                          float* __restrict__ out) {
    int idx = blockIdx.x * blockDim.x + threadIdx.x;   // (b*NT + t)
    if (idx < NB * NT) {
        const float2* p = (const float2*)(ws_fc + (size_t)idx * 4);
        out[idx * 2 + 0] = bfc[0] + p[0].x + p[1].x;
        out[idx * 2 + 1] = bfc[1] + p[0].y + p[1].y;
    }
}

// ---- safety-net fallback (ws too small): dense branchy loops, inline FC ----
__global__ __launch_bounds__(512)
void dgru_raw(const float* __restrict__ x,
              const float* __restrict__ wih0, const float* __restrict__ whh0,
              const float* __restrict__ wih1, const float* __restrict__ whh1,
              const float* __restrict__ bih0, const float* __restrict__ bhh0,
              const float* __restrict__ bih1, const float* __restrict__ bhh1,
              const float* __restrict__ wfc,  const float* __restrict__ bfc,
              float* __restrict__ out) {
    __shared__ float s_dx0[8];
    __shared__ float s_xp0[8];
    __shared__ float s_dh0[HID];
    __shared__ float s_dx1[HID];
    __shared__ float s_dh1[HID];
    __shared__ float s_part[16];

    const int j = threadIdx.x;
    const int b = blockIdx.x;
    float h0 = 0.f, h0p = 0.f, xp1 = 0.f, h1 = 0.f, h1p = 0.f;
    float cr0 = bih0[j] + bhh0[j];
    float cz0 = bih0[HID + j] + bhh0[HID + j];
    float cn0 = bih0[2*HID + j];
    float cnh0 = bhh0[2*HID + j];
    float cr1 = bih1[j] + bhh1[j];
    float cz1 = bih1[HID + j] + bhh1[HID + j];
    float cn1 = bih1[2*HID + j];
    float cnh1 = bhh1[2*HID + j];
    if (j < 8) { s_xp0[j] = 0.f; s_dx0[j] = 0.f; }
    const float wfc0 = wfc[j], wfc1 = wfc[HID + j];
    __syncthreads();

    for (int t = 0; t < NT; ++t) {
        float d = h0 - h0p;
        if (fabsf(d) < THH) d = 0.f; else h0p = h0;
        s_dh0[j] = d;
        if (j < 6) {
            float iv = x[(b * NT + t) * 2 + 0];
            float qv = x[(b * NT + t) * 2 + 1];
            float amp = sqrtf(iv * iv + qv * qv);
            float f;
            if      (j == 0) f = iv;
            else if (j == 1) f = qv;
            else if (j == 2) f = amp;
            else if (j == 3) f = amp * amp * amp;
            else if (j == 4) f = qv / amp;
            else             f = iv / amp;
            float dx = f - s_xp0[j];
            if (fabsf(dx) < THX) dx = 0.f; else s_xp0[j] = f;
            s_dx0[j] = dx;
        }
        __syncthreads();
        {
            float ar = cr0, az = cz0, an = cn0, anh = cnh0;
            #pragma unroll
            for (int f = 0; f < 6; ++f) {
                float dv = s_dx0[f];
                ar += dv * wih0[j * 6 + f];
                az += dv * wih0[(HID + j) * 6 + f];
                an += dv * wih0[(2*HID + j) * 6 + f];
            }
            for (int k = 0; k < HID; ++k) {
                float dv = s_dh0[k];
                if (dv != 0.f) {
                    ar  += dv * whh0[j * HID + k];
                    az  += dv * whh0[(HID + j) * HID + k];
                    anh += dv * whh0[(2*HID + j) * HID + k];
                }
            }
            cr0 = ar; cz0 = az; cn0 = an; cnh0 = anh;
            float r = 1.f / (1.f + expf(-ar));
            float z = 1.f / (1.f + expf(-az));
            float n = tanhf(an + r * anh);
            h0 = (1.f - z) * n + z * h0;
        }
        float dxv = h0 - xp1;
        if (fabsf(dxv) < THX) dxv = 0.f; else xp1 = h0;
        s_dx1[j] = dxv;
        float dhv = h1 - h1p;
        if (fabsf(dhv) < THH) dhv = 0.f; else h1p = h1;
        s_dh1[j] = dhv;
        __syncthreads();
        {
            float ar = cr1, az = cz1, an = cn1, anh = cnh1;
            for (int k = 0; k < HID; ++k) {
                float dv = s_dx1[k];
                if (dv != 0.f) {
                    ar += dv * wih1[j * HID + k];
                    az += dv * wih1[(HID + j) * HID + k];
                    an += dv * wih1[(2*HID + j) * HID + k];
                }
            }
            for (int k = 0; k < HID; ++k) {
                float dv = s_dh1[k];
                if (dv != 0.f) {
                    ar  += dv * whh1[j * HID + k];
                    az  += dv * whh1[(HID + j) * HID + k];
                    anh += dv * whh1[(2*HID + j) * HID + k];
                }
            }
            cr1 = ar; cz1 = az; cn1 = an; cnh1 = anh;
            float r = 1.f / (1.f + expf(-ar));
            float z = 1.f / (1.f + expf(-az));
            float n = tanhf(an + r * anh);
            h1 = (1.f - z) * n + z * h1;
        }
        float p0 = h1 * wfc0, p1 = h1 * wfc1;
        #pragma unroll
        for (int off = 32; off > 0; off >>= 1) {
            p0 += __shfl_down(p0, off, 64);
            p1 += __shfl_down(p1, off, 64);
        }
        if ((j & 63) == 0) { s_part[(j >> 6) * 2] = p0; s_part[(j >> 6) * 2 + 1] = p1; }
        __syncthreads();
        if (j == 0) {
            float o0 = bfc[0], o1 = bfc[1];
            #pragma unroll
            for (int w = 0; w < 8; ++w) { o0 += s_part[w * 2]; o1 += s_part[w * 2 + 1]; }
            out[(b * NT + t) * 2 + 0] = o0;
            out[(b * NT + t) * 2 + 1] = o1;
        }
    }
}

extern "C" void kernel_launch(void* const* d_in, const int* in_sizes, int n_in,
                              void* d_out, int out_size, void* d_ws, size_t ws_size,
                              hipStream_t stream) {
    const float* x    = (const float*)d_in[0];
    // d_in[1] = h_0 : reference zero-inits h, input unused
    const float* wih0 = (const float*)d_in[2];
    const float* whh0 = (const float*)d_in[3];
    const float* bih0 = (const float*)d_in[4];
    const float* bhh0 = (const float*)d_in[5];
    const float* wih1 = (const float*)d_in[6];
    const float* whh1 = (const float*)d_in[7];
    const float* bih1 = (const float*)d_in[8];
    const float* bhh1 = (const float*)d_in[9];
    const float* wfc  = (const float*)d_in[10];
    const float* bfc  = (const float*)d_in[11];
    float* out = (float*)d_out;

    const size_t MAT3    = (size_t)HID * 1536 * sizeof(float);     // 3 MiB each
    const size_t o_ih0   = 0;                                       // 36,864 B
    const size_t o_hh0   = 6 * 1536 * sizeof(float);
    const size_t o_ih1   = o_hh0 + MAT3;
    const size_t o_hh1   = o_ih1 + MAT3;
    const size_t o_lists = o_hh1 + MAT3;
    const size_t LISTS_B = (size_t)3 * 2 * NB * 2 * 256 * 8;        // 1.5 MiB
    const size_t o_cnts  = o_lists + LISTS_B;
    const size_t o_bars  = o_cnts + 3 * 2 * NB * 2 * sizeof(int);   // 3072 B
    const size_t o_fc    = o_bars + NB * sizeof(int);
    const size_t FCB     = (size_t)NB * NT * 4 * sizeof(float);     // 1 MiB
    const size_t need    = o_fc + FCB;                              // ~11.6 MiB

    if (ws_size >= need) {
        float* wt_ih0 = (float*)((char*)d_ws + o_ih0);
        float* wt_hh0 = (float*)((char*)d_ws + o_hh0);
        float* wt_ih1 = (float*)((char*)d_ws + o_ih1);
        float* wt_hh1 = (float*)((char*)d_ws + o_hh1);
        uint2* g_lists = (uint2*)((char*)d_ws + o_lists);
        int*   g_cnts  = (int*)((char*)d_ws + o_cnts);
        int*   g_bars  = (int*)((char*)d_ws + o_bars);
        float* g_fc    = (float*)((char*)d_ws + o_fc);

        pack_ih0<<<(6 * HID + 255) / 256, 256, 0, stream>>>(wih0, wt_ih0);
        pack_h3<<<(HID * HID + 255) / 256, 256, 0, stream>>>(whh0, wt_hh0);
        pack_h3<<<(HID * HID + 255) / 256, 256, 0, stream>>>(wih1, wt_ih1);
        pack_h3<<<(HID * HID + 255) / 256, 256, 0, stream>>>(whh1, wt_hh1);
        init_ws<<<1, 1024, 0, stream>>>(g_cnts, g_bars);
        dgru_split<<<4 * NB, 1024, 0, stream>>>(x, wt_ih0, wt_hh0, wt_ih1, wt_hh1,
                                                bih0, bhh0, bih1, bhh1, wfc,
                                                g_lists, g_cnts, g_bars, g_fc);
        fc_reduce<<<(NB * NT + 255) / 256, 256, 0, stream>>>(g_fc, bfc, out);
    } else {
        dgru_raw<<<NB, HID, 0, stream>>>(x, wih0, whh0, wih1, whh1,
                                         bih0, bhh0, bih1, bhh1, wfc, bfc, out);
    }
}

// Round 10
// 43875.317 us; speedup vs baseline: 4.5821x; 4.5821x over previous
//
#include <hip/hip_runtime.h>

#define HID 512
#define NB  64
#define NT  1024
#define THX 0.1f
#define THH 0.05f

// ---- prep: pack W_ih_l0 [1536][6] f32 -> [6][512]{r,z,n} float3 ----
__global__ void pack_ih0(const float* __restrict__ src, float* __restrict__ dst) {
    int idx = blockIdx.x * blockDim.x + threadIdx.x;
    if (idx < 6 * HID) {
        int f = idx / HID, j = idx % HID;
        dst[f * 1536 + j * 3 + 0] = src[(0 * HID + j) * 6 + f];
        dst[f * 1536 + j * 3 + 1] = src[(1 * HID + j) * 6 + f];
        dst[f * 1536 + j * 3 + 2] = src[(2 * HID + j) * 6 + f];
    }
}

// ---- prep: pack a [1536][512] f32 matrix -> [512(k)][512(j)]{r,z,n} float3 ----
__global__ void pack_h3(const float* __restrict__ src, float* __restrict__ dst) {
    int idx = blockIdx.x * blockDim.x + threadIdx.x;
    if (idx < HID * HID) {
        int k = idx / HID, j = idx % HID;
        dst[k * 1536 + j * 3 + 0] = src[(0 * HID + j) * HID + k];
        dst[k * 1536 + j * 3 + 1] = src[(1 * HID + j) * HID + k];
        dst[k * 1536 + j * 3 + 2] = src[(2 * HID + j) * HID + k];
    }
}

// ---- init: zero list counts + padded barrier counters (every launch) ----
__global__ void init_ws(int* __restrict__ cnts, int* __restrict__ bars) {
    int i = blockIdx.x * blockDim.x + threadIdx.x;
    if (i < 3 * 2 * NB * 2) cnts[i] = 0;
    if (i < NB * 64) bars[i] = 0;
}

__device__ __forceinline__ int cidx(int kind, int slot, int b, int half) {
    return ((kind * 2 + slot) * NB + b) * 2 + half;
}
__device__ __forceinline__ int lofs(int kind, int slot, int b, int half) {
    return (((kind * 2 + slot) * NB + b) * 2 + half) * 256;   // uint2 units
}

// ---- coherent (agent-scope, relaxed) loads: bypass stale L2 WITHOUT any
// cache-invalidating fence. Only cross-WG data (cnts, list entries) uses
// these; weight reads stay plain -> clean L2 lines stay resident. ----
__device__ __forceinline__ int ld_cnt(const int* p) {
    return __hip_atomic_load(p, __ATOMIC_RELAXED, __HIP_MEMORY_SCOPE_AGENT);
}
__device__ __forceinline__ uint2 ld_ent(const uint2* p) {
    unsigned long long r = __hip_atomic_load((const unsigned long long*)p,
                             __ATOMIC_RELAXED, __HIP_MEMORY_SCOPE_AGENT);
    return make_uint2((unsigned)r, (unsigned)(r >> 32));
}

// ---- depth-8 software-pipelined sparse MAC (named scalars, exact order) ----
// KIND 0 = ih-type (all roles -> accP); KIND 1 = hh-type (role2 -> accS).
// n is a multiple of 8; pad entries are (k=0, v=0) -> exact +0 adds.
// Loads are issued 8 entries ahead of use in program order; consumption is
// strictly ascending -> bitwise-identical accumulation vs rounds 3-9.
template <int KIND>
__device__ __forceinline__ void mac_pipe(const uint2* __restrict__ sl, int n,
                                         const float* __restrict__ wt, int role,
                                         float& accP, float& accS) {
    if (n <= 0) return;
    float v0, v1, v2, v3, v4, v5, v6, v7;
    float w0, w1, w2, w3, w4, w5, w6, w7;
#define PIPE_ISSUE(S, IDX) { uint2 e_ = sl[(IDX)]; v##S = __uint_as_float(e_.y); \
                             w##S = wt[(size_t)e_.x * 1536]; }
#define PIPE_CONS(S, NXT, MORE) { float tv_ = v##S, tw_ = w##S; \
    if (MORE) PIPE_ISSUE(S, (NXT)) \
    if (KIND == 1) { float p_ = tv_ * tw_; if (role == 2) accS += p_; else accP += p_; } \
    else { accP += tv_ * tw_; } }
    PIPE_ISSUE(0, 0) PIPE_ISSUE(1, 1) PIPE_ISSUE(2, 2) PIPE_ISSUE(3, 3)
    PIPE_ISSUE(4, 4) PIPE_ISSUE(5, 5) PIPE_ISSUE(6, 6) PIPE_ISSUE(7, 7)
    #pragma unroll 1
    for (int i = 0; i < n; i += 8) {
        const int nx = i + 8;
        const bool more = nx < n;
        PIPE_CONS(0, nx + 0, more)
        PIPE_CONS(1, nx + 1, more)
        PIPE_CONS(2, nx + 2, more)
        PIPE_CONS(3, nx + 3, more)
        PIPE_CONS(4, nx + 4, more)
        PIPE_CONS(5, nx + 5, more)
        PIPE_CONS(6, nx + 6, more)
        PIPE_CONS(7, nx + 7, more)
    }
#undef PIPE_ISSUE
#undef PIPE_CONS
}

// ---- main kernel: 256 WGs = 64 batches x {L0,L1} x {j-half lo,hi} ----
// wgid%8 maps same-(layer,half) WGs to the same XCD -> each XCD's L2 holds
// only a 1.5-3MB weight slice -> L2-resident (round 9: FETCH 100GB->1.7GB).
// launch_bounds(1024,4): 16 waves/WG = 4/SIMD -> VGPR budget 128 (round 6-9
// implicitly targeted 64 and serialized all load batching).
__global__ __launch_bounds__(1024, 4)
void dgru_split(const float* __restrict__ x,
                const float* __restrict__ wih0p,   // [6][512] float3
                const float* __restrict__ whh0p,   // [512][512] float3
                const float* __restrict__ wih1p,
                const float* __restrict__ whh1p,
                const float* __restrict__ bih0, const float* __restrict__ bhh0,
                const float* __restrict__ bih1, const float* __restrict__ bhh1,
                const float* __restrict__ wfc,
                uint2* __restrict__ lists, int* __restrict__ cnts,
                int* __restrict__ bars, float* __restrict__ ws_fc) {
    __shared__ float s_x[2 * NT];                  // 8 KB (L0 only)
    __shared__ float s_dx0[8];
    __shared__ float s_xp0[8];
    __shared__ uint2 s_l1[HID + 8];
    __shared__ uint2 s_l2[HID + 8];
    __shared__ int   s_c1[16], s_c2[16];
    __shared__ float s_fcp[16][2];

    const int wgid  = blockIdx.x;
    const int bq    = wgid >> 2;
    const int layer = (wgid >> 1) & 1;
    const int half  = wgid & 1;
    const int tid   = threadIdx.x;
    const int lane  = tid & 63;
    const int wave  = tid >> 6;
    const int u     = tid >> 2;
    const int role  = tid & 3;
    const int uu    = half * 256 + u;

    const float* bih = layer ? bih1 : bih0;
    const float* bhh = layer ? bhh1 : bhh0;

    // carries: accP = {ar | az | an} by role; accS = anh on role2
    float accP = 0.f, accS = 0.f;
    if (role == 0)      accP = bih[uu]         + bhh[uu];
    else if (role == 1) accP = bih[HID + uu]   + bhh[HID + uu];
    else if (role == 2) { accP = bih[2*HID + uu]; accS = bhh[2*HID + uu]; }

    float h = 0.f, hp = 0.f, xp1 = 0.f;
    float wfc0 = 0.f, wfc1 = 0.f;
    if (layer == 1) { wfc0 = wfc[uu]; wfc1 = wfc[HID + uu]; }

    if (layer == 0)
        for (int i = tid; i < 2 * NT; i += 1024) s_x[i] = x[bq * 2 * NT + i];
    if (tid < 8) { s_xp0[tid] = 0.f; s_dx0[tid] = 0.f; }
    __syncthreads();

    const float* wtH0 = whh0p + uu * 3 + role;
    const float* wtI1 = wih1p + uu * 3 + role;
    const float* wtH1 = whh1p + uu * 3 + role;

    for (int t = 0; t <= NT; ++t) {
        const int rs = t & 1, ps = (t + 1) & 1;
        if (layer == 0) {
            if (t < NT) {
                // ---- stage merged listA(rs): lo sublist then hi (k ascending) ----
                int cLo = ld_cnt(&cnts[cidx(0, rs, bq, 0)]);
                int cHi = ld_cnt(&cnts[cidx(0, rs, bq, 1)]);
                int ntot = cLo + cHi, n1 = (ntot + 7) & ~7;
                const uint2* gLo = lists + lofs(0, rs, bq, 0);
                const uint2* gHi = lists + lofs(0, rs, bq, 1);
                if (tid < cLo)       s_l1[tid] = ld_ent(&gLo[tid]);
                else if (tid < ntot) s_l1[tid] = ld_ent(&gHi[tid - cLo]);
                else if (tid < n1)   s_l1[tid] = make_uint2(0u, 0u);
                // ---- input features for step t ----
                if (tid < 6) {
                    float iv = s_x[2 * t], qv = s_x[2 * t + 1];
                    float amp = sqrtf(iv * iv + qv * qv);
                    float f;
                    if      (tid == 0) f = iv;
                    else if (tid == 1) f = qv;
                    else if (tid == 2) f = amp;
                    else if (tid == 3) f = amp * amp * amp;
                    else if (tid == 4) f = qv / amp;
                    else               f = iv / amp;
                    float dx = f - s_xp0[tid];
                    if (fabsf(dx) < THX) dx = 0.f; else s_xp0[tid] = f;
                    s_dx0[tid] = dx;
                }
                __syncthreads();
                // ---- dense ih0 (6 features; dv==0 adds exact +0) ----
                #pragma unroll
                for (int f = 0; f < 6; ++f) {
                    float dv = s_dx0[f];
                    float w = wih0p[f * 1536 + uu * 3 + role];
                    accP += dv * w;
                }
                // ---- listA MAC over whh0 (hh-type, depth-8 pipelined) ----
                mac_pipe<1>(s_l1, n1, wtH0, role, accP, accS);
                // ---- gates (role0 meaningful) ----
                const int bl = lane & ~3;
                float ar  = __shfl(accP, bl + 0, 64);
                float az  = __shfl(accP, bl + 1, 64);
                float an  = __shfl(accP, bl + 2, 64);
                float anh = __shfl(accS, bl + 2, 64);
                float r = 1.f / (1.f + expf(-ar));
                float z = 1.f / (1.f + expf(-az));
                float n = tanhf(an + r * anh);
                h = (1.f - z) * n + z * h;
                // ---- deltas + dual compaction (A' = dh0, B' = dx1) ----
                float dA = h - hp;  if (fabsf(dA) < THH) dA = 0.f; else hp = h;
                float dB = h - xp1; if (fabsf(dB) < THX) dB = 0.f; else xp1 = h;
                bool nzA = (role == 0) && (dA != 0.f);
                bool nzB = (role == 0) && (dB != 0.f);
                unsigned long long mA = __ballot(nzA);
                unsigned long long mB = __ballot(nzB);
                if (lane == 0) { s_c1[wave] = __popcll(mA); s_c2[wave] = __popcll(mB); }
                __syncthreads();
                int baseA = 0, baseB = 0, totA = 0, totB = 0;
                #pragma unroll
                for (int w = 0; w < 16; ++w) {
                    int c1 = s_c1[w], c2 = s_c2[w];
                    baseA += (w < wave) ? c1 : 0;  totA += c1;
                    baseB += (w < wave) ? c2 : 0;  totB += c2;
                }
                uint2* outA = lists + lofs(0, ps, bq, half);
                uint2* outB = lists + lofs(1, ps, bq, half);
                unsigned long long below = (1ull << lane) - 1;
                if (nzA) outA[baseA + __popcll(mA & below)] = make_uint2((unsigned)uu, __float_as_uint(dA));
                if (nzB) outB[baseB + __popcll(mB & below)] = make_uint2((unsigned)uu, __float_as_uint(dB));
                if (tid == 0) {
                    cnts[cidx(0, ps, bq, half)] = totA;
                    cnts[cidx(1, ps, bq, half)] = totB;
                }
            }
        } else {
            if (t > 0) {
                // ---- L1 runs step t-1: stage listB(rs) and listC(rs) ----
                int cBlo = ld_cnt(&cnts[cidx(1, rs, bq, 0)]);
                int cBhi = ld_cnt(&cnts[cidx(1, rs, bq, 1)]);
                int cClo = ld_cnt(&cnts[cidx(2, rs, bq, 0)]);
                int cChi = ld_cnt(&cnts[cidx(2, rs, bq, 1)]);
                int ntB = cBlo + cBhi, nB = (ntB + 7) & ~7;
                int ntC = cClo + cChi, nC = (ntC + 7) & ~7;
                const uint2* gBlo = lists + lofs(1, rs, bq, 0);
                const uint2* gBhi = lists + lofs(1, rs, bq, 1);
                const uint2* gClo = lists + lofs(2, rs, bq, 0);
                const uint2* gChi = lists + lofs(2, rs, bq, 1);
                if (tid < cBlo)      s_l1[tid] = ld_ent(&gBlo[tid]);
                else if (tid < ntB)  s_l1[tid] = ld_ent(&gBhi[tid - cBlo]);
                else if (tid < nB)   s_l1[tid] = make_uint2(0u, 0u);
                if (tid < cClo)      s_l2[tid] = ld_ent(&gClo[tid]);
                else if (tid < ntC)  s_l2[tid] = ld_ent(&gChi[tid - cClo]);
                else if (tid < nC)   s_l2[tid] = make_uint2(0u, 0u);
                __syncthreads();
                // listB over wih1 (ih-type), then listC over whh1 (hh-type)
                mac_pipe<0>(s_l1, nB, wtI1, role, accP, accS);
                mac_pipe<1>(s_l2, nC, wtH1, role, accP, accS);
                const int bl = lane & ~3;
                float ar  = __shfl(accP, bl + 0, 64);
                float az  = __shfl(accP, bl + 1, 64);
                float an  = __shfl(accP, bl + 2, 64);
                float anh = __shfl(accS, bl + 2, 64);
                float r = 1.f / (1.f + expf(-ar));
                float z = 1.f / (1.f + expf(-az));
                float n = tanhf(an + r * anh);
                h = (1.f - z) * n + z * h;
                // FC partials (role0 lanes), tree within wave, serial over waves
                float p0 = (role == 0) ? h * wfc0 : 0.f;
                float p1 = (role == 0) ? h * wfc1 : 0.f;
                p0 += __shfl_down(p0, 4, 64);  p1 += __shfl_down(p1, 4, 64);
                p0 += __shfl_down(p0, 8, 64);  p1 += __shfl_down(p1, 8, 64);
                p0 += __shfl_down(p0, 16, 64); p1 += __shfl_down(p1, 16, 64);
                p0 += __shfl_down(p0, 32, 64); p1 += __shfl_down(p1, 32, 64);
                if (lane == 0) { s_fcp[wave][0] = p0; s_fcp[wave][1] = p1; }
                __syncthreads();
                if (tid == 0) {
                    float q0 = 0.f, q1 = 0.f;
                    #pragma unroll
                    for (int w = 0; w < 16; ++w) { q0 += s_fcp[w][0]; q1 += s_fcp[w][1]; }
                    float2* dst = (float2*)(ws_fc + ((size_t)(bq * NT + (t - 1)) * 2 + half) * 2);
                    *dst = make_float2(q0, q1);
                }
            }
            if (t < NT) {
                // ---- dC publish (dh1 after step t-1) ----
                float dC = h - hp; if (fabsf(dC) < THH) dC = 0.f; else hp = h;
                bool nzC = (role == 0) && (dC != 0.f);
                unsigned long long mC = __ballot(nzC);
                if (lane == 0) s_c1[wave] = __popcll(mC);
                __syncthreads();
                int baseC = 0, totC = 0;
                #pragma unroll
                for (int w = 0; w < 16; ++w) {
                    int c = s_c1[w];
                    baseC += (w < wave) ? c : 0;  totC += c;
                }
                uint2* outC = lists + lofs(2, ps, bq, half);
                if (nzC) outC[baseC + __popcll(mC & ((1ull << lane) - 1))] =
                    make_uint2((unsigned)uu, __float_as_uint(dC));
                if (tid == 0) cnts[cidx(2, ps, bq, half)] = totC;
            }
        }
        // ---- quad barrier: padded flag, release on producer side only,
        //      RELAXED polling (no acquire / no threadfence -> no L2 flush) ----
        if (t < NT) {
            __syncthreads();     // all waves' global stores drained (vmcnt at barrier)
            if (tid == 0) {
                __hip_atomic_fetch_add(&bars[bq * 64], 1, __ATOMIC_RELEASE,
                                       __HIP_MEMORY_SCOPE_AGENT);
                while (__hip_atomic_load(&bars[bq * 64], __ATOMIC_RELAXED,
                                         __HIP_MEMORY_SCOPE_AGENT) < 4 * (t + 1))
                    __builtin_amdgcn_s_sleep(8);
            }
            __syncthreads();
        }
    }
}

// ---- epilogue: deterministic FC reduction (lo half + hi half + bias) ----
__global__ void fc_reduce(const float* __restrict__ ws_fc,
                          const float* __restrict__ bfc,
                          float* __restrict__ out) {
    int idx = blockIdx.x * blockDim.x + threadIdx.x;   // (b*NT + t)
    if (idx < NB * NT) {
        const float2* p = (const float2*)(ws_fc + (size_t)idx * 4);
        out[idx * 2 + 0] = bfc[0] + p[0].x + p[1].x;
        out[idx * 2 + 1] = bfc[1] + p[0].y + p[1].y;
    }
}

// ---- safety-net fallback (ws too small): dense branchy loops, inline FC ----
__global__ __launch_bounds__(512)
void dgru_raw(const float* __restrict__ x,
              const float* __restrict__ wih0, const float* __restrict__ whh0,
              const float* __restrict__ wih1, const float* __restrict__ whh1,
              const float* __restrict__ bih0, const float* __restrict__ bhh0,
              const float* __restrict__ bih1, const float* __restrict__ bhh1,
              const float* __restrict__ wfc,  const float* __restrict__ bfc,
              float* __restrict__ out) {
    __shared__ float s_dx0[8];
    __shared__ float s_xp0[8];
    __shared__ float s_dh0[HID];
    __shared__ float s_dx1[HID];
    __shared__ float s_dh1[HID];
    __shared__ float s_part[16];

    const int j = threadIdx.x;
    const int b = blockIdx.x;
    float h0 = 0.f, h0p = 0.f, xp1 = 0.f, h1 = 0.f, h1p = 0.f;
    float cr0 = bih0[j] + bhh0[j];
    float cz0 = bih0[HID + j] + bhh0[HID + j];
    float cn0 = bih0[2*HID + j];
    float cnh0 = bhh0[2*HID + j];
    float cr1 = bih1[j] + bhh1[j];
    float cz1 = bih1[HID + j] + bhh1[HID + j];
    float cn1 = bih1[2*HID + j];
    float cnh1 = bhh1[2*HID + j];
    if (j < 8) { s_xp0[j] = 0.f; s_dx0[j] = 0.f; }
    const float wfc0 = wfc[j], wfc1 = wfc[HID + j];
    __syncthreads();

    for (int t = 0; t < NT; ++t) {
        float d = h0 - h0p;
        if (fabsf(d) < THH) d = 0.f; else h0p = h0;
        s_dh0[j] = d;
        if (j < 6) {
            float iv = x[(b * NT + t) * 2 + 0];
            float qv = x[(b * NT + t) * 2 + 1];
            float amp = sqrtf(iv * iv + qv * qv);
            float f;
            if      (j == 0) f = iv;
            else if (j == 1) f = qv;
            else if (j == 2) f = amp;
            else if (j == 3) f = amp * amp * amp;
            else if (j == 4) f = qv / amp;
            else             f = iv / amp;
            float dx = f - s_xp0[j];
            if (fabsf(dx) < THX) dx = 0.f; else s_xp0[j] = f;
            s_dx0[j] = dx;
        }
        __syncthreads();
        {
            float ar = cr0, az = cz0, an = cn0, anh = cnh0;
            #pragma unroll
            for (int f = 0; f < 6; ++f) {
                float dv = s_dx0[f];
                ar += dv * wih0[j * 6 + f];
                az += dv * wih0[(HID + j) * 6 + f];
                an += dv * wih0[(2*HID + j) * 6 + f];
            }
            for (int k = 0; k < HID; ++k) {
                float dv = s_dh0[k];
                if (dv != 0.f) {
                    ar  += dv * whh0[j * HID + k];
                    az  += dv * whh0[(HID + j) * HID + k];
                    anh += dv * whh0[(2*HID + j) * HID + k];
                }
            }
            cr0 = ar; cz0 = az; cn0 = an; cnh0 = anh;
            float r = 1.f / (1.f + expf(-ar));
            float z = 1.f / (1.f + expf(-az));
            float n = tanhf(an + r * anh);
            h0 = (1.f - z) * n + z * h0;
        }
        float dxv = h0 - xp1;
        if (fabsf(dxv) < THX) dxv = 0.f; else xp1 = h0;
        s_dx1[j] = dxv;
        float dhv = h1 - h1p;
        if (fabsf(dhv) < THH) dhv = 0.f; else h1p = h1;
        s_dh1[j] = dhv;
        __syncthreads();
        {
            float ar = cr1, az = cz1, an = cn1, anh = cnh1;
            for (int k = 0; k < HID; ++k) {
                float dv = s_dx1[k];
                if (dv != 0.f) {
                    ar += dv * wih1[j * HID + k];
                    az += dv * wih1[(HID + j) * HID + k];
                    an += dv * wih1[(2*HID + j) * HID + k];
                }
            }
            for (int k = 0; k < HID; ++k) {
                float dv = s_dh1[k];
                if (dv != 0.f) {
                    ar  += dv * whh1[j * HID + k];
                    az  += dv * whh1[(HID + j) * HID + k];
                    anh += dv * whh1[(2*HID + j) * HID + k];
                }
            }
            cr1 = ar; cz1 = az; cn1 = an; cnh1 = anh;
            float r = 1.f / (1.f + expf(-ar));
            float z = 1.f / (1.f + expf(-az));
            float n = tanhf(an + r * anh);
            h1 = (1.f - z) * n + z * h1;
        }
        float p0 = h1 * wfc0, p1 = h1 * wfc1;
        #pragma unroll
        for (int off = 32; off > 0; off >>= 1) {
            p0 += __shfl_down(p0, off, 64);
            p1 += __shfl_down(p1, off, 64);
        }
        if ((j & 63) == 0) { s_part[(j >> 6) * 2] = p0; s_part[(j >> 6) * 2 + 1] = p1; }
        __syncthreads();
        if (j == 0) {
            float o0 = bfc[0], o1 = bfc[1];
            #pragma unroll
            for (int w = 0; w < 8; ++w) { o0 += s_part[w * 2]; o1 += s_part[w * 2 + 1]; }
            out[(b * NT + t) * 2 + 0] = o0;
            out[(b * NT + t) * 2 + 1] = o1;
        }
    }
}

extern "C" void kernel_launch(void* const* d_in, const int* in_sizes, int n_in,
                              void* d_out, int out_size, void* d_ws, size_t ws_size,
                              hipStream_t stream) {
    const float* x    = (const float*)d_in[0];
    // d_in[1] = h_0 : reference zero-inits h, input unused
    const float* wih0 = (const float*)d_in[2];
    const float* whh0 = (const float*)d_in[3];
    const float* bih0 = (const float*)d_in[4];
    const float* bhh0 = (const float*)d_in[5];
    const float* wih1 = (const float*)d_in[6];
    const float* whh1 = (const float*)d_in[7];
    const float* bih1 = (const float*)d_in[8];
    const float* bhh1 = (const float*)d_in[9];
    const float* wfc  = (const float*)d_in[10];
    const float* bfc  = (const float*)d_in[11];
    float* out = (float*)d_out;

    const size_t MAT3    = (size_t)HID * 1536 * sizeof(float);     // 3 MiB each
    const size_t o_ih0   = 0;                                       // 36,864 B
    const size_t o_hh0   = 6 * 1536 * sizeof(float);
    const size_t o_ih1   = o_hh0 + MAT3;
    const size_t o_hh1   = o_ih1 + MAT3;
    const size_t o_lists = o_hh1 + MAT3;
    const size_t LISTS_B = (size_t)3 * 2 * NB * 2 * 256 * 8;        // 1.5 MiB
    const size_t o_cnts  = o_lists + LISTS_B;
    const size_t o_bars  = o_cnts + 3 * 2 * NB * 2 * sizeof(int);
    const size_t o_fc    = o_bars + (size_t)NB * 64 * sizeof(int);  // padded flags
    const size_t FCB     = (size_t)NB * NT * 4 * sizeof(float);     // 1 MiB
    const size_t need    = o_fc + FCB;                              // ~12 MiB

    if (ws_size >= need) {
        float* wt_ih0 = (float*)((char*)d_ws + o_ih0);
        float* wt_hh0 = (float*)((char*)d_ws + o_hh0);
        float* wt_ih1 = (float*)((char*)d_ws + o_ih1);
        float* wt_hh1 = (float*)((char*)d_ws + o_hh1);
        uint2* g_lists = (uint2*)((char*)d_ws + o_lists);
        int*   g_cnts  = (int*)((char*)d_ws + o_cnts);
        int*   g_bars  = (int*)((char*)d_ws + o_bars);
        float* g_fc    = (float*)((char*)d_ws + o_fc);

        pack_ih0<<<(6 * HID + 255) / 256, 256, 0, stream>>>(wih0, wt_ih0);
        pack_h3<<<(HID * HID + 255) / 256, 256, 0, stream>>>(whh0, wt_hh0);
        pack_h3<<<(HID * HID + 255) / 256, 256, 0, stream>>>(wih1, wt_ih1);
        pack_h3<<<(HID * HID + 255) / 256, 256, 0, stream>>>(whh1, wt_hh1);
        init_ws<<<4, 1024, 0, stream>>>(g_cnts, g_bars);
        dgru_split<<<4 * NB, 1024, 0, stream>>>(x, wt_ih0, wt_hh0, wt_ih1, wt_hh1,
                                                bih0, bhh0, bih1, bhh1, wfc,
                                                g_lists, g_cnts, g_bars, g_fc);
        fc_reduce<<<(NB * NT + 255) / 256, 256, 0, stream>>>(g_fc, bfc, out);
    } else {
        dgru_raw<<<NB, HID, 0, stream>>>(x, wih0, whh0, wih1, whh1,
                                         bih0, bhh0, bih1, bhh1, wfc, bfc, out);
    }
}